// Round 7
// baseline (781.948 us; speedup 1.0000x reference)
//
#include <hip/hip_runtime.h>
#include <hip/hip_fp16.h>
#include <math.h>

typedef unsigned short u16;
typedef u16 u16x8 __attribute__((ext_vector_type(8)));
typedef __bf16 bf16x8 __attribute__((ext_vector_type(8)));
typedef float f32x4 __attribute__((ext_vector_type(4)));

#define HID 200
#define G4H 800
#define TLEN 128
#define LATENT 128
#define NCODES 1024
#define DIN 768
#define DCOND 1536
#define NB 256
#define MROWS (NB * TLEN)
#define LDG 896
#define LDH1 256
#define LDH2 512
#define NOUT 768

__device__ __forceinline__ u16 f2b(float f) {
  union { float f; unsigned u; } v; v.f = f;
  unsigned r = v.u + 0x7fffu + ((v.u >> 16) & 1u);
  return (u16)(r >> 16);
}
__device__ __forceinline__ float b2f(u16 h) {
  union { unsigned u; float f; } v; v.u = ((unsigned)h) << 16;
  return v.f;
}
__device__ __forceinline__ float sigf(float x) { return 1.f / (1.f + __expf(-x)); }
__device__ __forceinline__ float tanh_fast(float x) {
  return 1.f - 2.f / (__expf(2.f * x) + 1.f);
}

// async global->LDS, 16B per lane
__device__ __forceinline__ void gl16(const void* g, void* l) {
  __builtin_amdgcn_global_load_lds(
      (const __attribute__((address_space(1))) void*)g,
      (__attribute__((address_space(3))) void*)l, 16, 0, 0);
}

__device__ __forceinline__ unsigned cvtpk(float a, float b) {
  unsigned r;
  asm("v_cvt_pk_bf16_f32 %0, %1, %2" : "=v"(r) : "v"(a), "v"(b));
  return r;
}

// ---------------- weight convert + pad ----------------
__global__ void cvt_pad(const float* __restrict__ src, u16* __restrict__ dst,
                        int nr, int nc, int lds, int col0, int NRp, int KP) {
  int i = blockIdx.x * blockDim.x + threadIdx.x;
  if (i >= NRp * KP) return;
  int r = i / KP, c = i - r * KP;
  float v = (r < nr && c < nc) ? src[(size_t)r * lds + col0 + c] : 0.f;
  dst[i] = f2b(v);
}

__global__ void pad_f32(const float* __restrict__ src, float* __restrict__ dst,
                        int n, int npad) {
  int i = blockIdx.x * blockDim.x + threadIdx.x;
  if (i < npad) dst[i] = (i < n) ? src[i] : 0.f;
}

// W_hh [800][200] f32 -> Wt2[k*400+r] = half2(W[r][k], W[r+400][k]);
// biasc[col<896] = b_ih+b_hh (0-padded) for the gates-GEMM epilogue.
__global__ void pack_whh2(const float* __restrict__ Whh, unsigned* __restrict__ Wt2,
                          const float* __restrict__ b_ih, const float* __restrict__ b_hh,
                          float* __restrict__ biasc) {
  int i = blockIdx.x * blockDim.x + threadIdx.x;
  if (i < 200 * 400) {
    int k = i / 400, r = i - k * 400;
    __half2 h = __floats2half2_rn(Whh[(size_t)r * HID + k], Whh[(size_t)(r + 400) * HID + k]);
    Wt2[i] = __builtin_bit_cast(unsigned, h);
  }
  if (i < LDG) biasc[i] = (i < G4H) ? (b_ih[i] + b_hh[i]) : 0.f;
}

// ---------------- bf16 MFMA GEMM: C[M,N] = A[M,K] * B[N,K]^T (+epilogue) ----------------
enum { EPI_GATES = 0, EPI_H1 = 1, EPI_H2 = 2, EPI_OUT = 3 };

__device__ __forceinline__ f32x4 mfma16(bf16x8 a, bf16x8 b, f32x4 c) {
  return __builtin_amdgcn_mfma_f32_16x16x32_bf16(a, b, c, 0, 0, 0);
}

template<bool AF32, int EPI>
__global__ __launch_bounds__(256) void gemm_bf16(
    const void* __restrict__ Ap, const u16* __restrict__ Bp,
    void* __restrict__ Cp, int K, int ldc, const float* __restrict__ bias) {
  __shared__ __attribute__((aligned(16))) char AsRaw[AF32 ? 128 * 32 * 4 : 128 * 32 * 2];
  __shared__ __attribute__((aligned(16))) u16 Bs[128 * 32];
  float* Asf = (float*)AsRaw;
  u16* As16 = (u16*)AsRaw;

  const int t = threadIdx.x;
  const int tileN = blockIdx.x * 128;
  const int tileM = blockIdx.y * 128;
  const int l = t & 63;
  const int w = t >> 6;
  const int wr = (w >> 1) * 64;
  const int wc = (w & 1) * 64;
  const int fr = l & 15;
  const int fg = l >> 4;

  const u16* bsrc[2];
  u16* bdst[2];
#pragma unroll
  for (int j = 0; j < 2; ++j) {
    int tb = w * 1024 + j * 4096 + (t & 63) * 16;
    int row = tb >> 6, gd = (tb >> 4) & 3;
    bsrc[j] = Bp + (size_t)(tileN + row) * K + ((gd ^ ((row >> 1) & 3)) << 3);
    bdst[j] = Bs + w * 512 + j * 2048;
  }
  const float* asrcF[4];
  float* adstF[4];
  const u16* asrcH[2];
  u16* adstH[2];
  if constexpr (AF32) {
#pragma unroll
    for (int j = 0; j < 4; ++j) {
      int tb = w * 1024 + j * 4096 + (t & 63) * 16;
      int row = tb >> 7, gd = (tb >> 4) & 7;
      asrcF[j] = (const float*)Ap + (size_t)(tileM + row) * K + ((gd ^ (row & 7)) << 2);
      adstF[j] = Asf + w * 256 + j * 1024;
    }
  } else {
#pragma unroll
    for (int j = 0; j < 2; ++j) {
      int tb = w * 1024 + j * 4096 + (t & 63) * 16;
      int row = tb >> 6, gd = (tb >> 4) & 3;
      asrcH[j] = (const u16*)Ap + (size_t)(tileM + row) * K + ((gd ^ ((row >> 1) & 3)) << 3);
      adstH[j] = As16 + w * 512 + j * 2048;
    }
  }

  f32x4 acc[4][4];
#pragma unroll
  for (int m = 0; m < 4; ++m)
#pragma unroll
    for (int n = 0; n < 4; ++n) {
      f32x4 z = {0.f, 0.f, 0.f, 0.f};
      acc[m][n] = z;
    }

  for (int k0 = 0; k0 < K; k0 += 32) {
#pragma unroll
    for (int j = 0; j < 2; ++j) { gl16(bsrc[j], bdst[j]); bsrc[j] += 32; }
    if constexpr (AF32) {
#pragma unroll
      for (int j = 0; j < 4; ++j) { gl16(asrcF[j], adstF[j]); asrcF[j] += 32; }
    } else {
#pragma unroll
      for (int j = 0; j < 2; ++j) { gl16(asrcH[j], adstH[j]); asrcH[j] += 32; }
    }
    __syncthreads();

    bf16x8 av[4], bv[4];
#pragma unroll
    for (int m = 0; m < 4; ++m) {
      const int row = wr + m * 16 + fr;
      if constexpr (AF32) {
        const int g0 = (2 * fg) ^ (row & 7);
        const int g1 = (2 * fg + 1) ^ (row & 7);
        float4 p0 = *(const float4*)(Asf + row * 32 + g0 * 4);
        float4 p1 = *(const float4*)(Asf + row * 32 + g1 * 4);
        uint4 u;
        u.x = cvtpk(p0.x, p0.y); u.y = cvtpk(p0.z, p0.w);
        u.z = cvtpk(p1.x, p1.y); u.w = cvtpk(p1.z, p1.w);
        av[m] = __builtin_bit_cast(bf16x8, u);
      } else {
        const int g = fg ^ ((row >> 1) & 3);
        av[m] = __builtin_bit_cast(bf16x8, *(const u16x8*)(As16 + row * 32 + g * 8));
      }
    }
#pragma unroll
    for (int n = 0; n < 4; ++n) {
      const int row = wc + n * 16 + fr;
      const int g = fg ^ ((row >> 1) & 3);
      bv[n] = __builtin_bit_cast(bf16x8, *(const u16x8*)(Bs + row * 32 + g * 8));
    }
#pragma unroll
    for (int m = 0; m < 4; ++m)
#pragma unroll
      for (int n = 0; n < 4; ++n)
        acc[m][n] = mfma16(av[m], bv[n], acc[m][n]);
    __syncthreads();
  }

#pragma unroll
  for (int m = 0; m < 4; ++m) {
#pragma unroll
    for (int n = 0; n < 4; ++n) {
      const int gcol = tileN + wc + n * 16 + fr;
      const int growb = tileM + wr + m * 16 + fg * 4;
#pragma unroll
      for (int r = 0; r < 4; ++r) {
        const int grow = growb + r;
        float v = acc[m][n][r];
        if constexpr (EPI == EPI_GATES) {
          v += bias[gcol];   // b_ih + b_hh folded here
          ((u16*)Cp)[(size_t)grow * ldc + gcol] = f2b(v);
        } else if constexpr (EPI == EPI_H1) {
          v += bias[(grow >> 7) * 256 + gcol];
          v = fmaxf(v, 0.f);
          ((u16*)Cp)[(size_t)grow * ldc + gcol] = f2b(v);
        } else if constexpr (EPI == EPI_H2) {
          v += bias[gcol];
          v = fmaxf(v, 0.f);
          ((u16*)Cp)[(size_t)grow * ldc + gcol] = f2b(v);
        } else {
          v += bias[gcol];
          ((float*)Cp)[(size_t)grow * ldc + gcol] = sigf(v);
        }
      }
    }
  }
}

// ---------------- fused LSTM scan + encoder + VQ + p1 ----------------
// 448 threads (7 waves) per block, one block per batch element.
// Thread r<400 owns gate rows {r, r+400} over all 200 k as 200 half2 dwords
// PINNED IN AGPRs via inline asm ("a" constraints) -> arch-VGPR pressure ~30,
// immune to the allocator's 64/128 arch budget; no spill possible.
// Dot: v_pk_fma_f16 with h-splat via op_sel (2 MACs/instr, validated R2/R3).

#define G0  aw0,aw1,aw2,aw3,aw4,aw5,aw6,aw7
#define G1  aw8,aw9,aw10,aw11,aw12,aw13,aw14,aw15
#define G2  aw16,aw17,aw18,aw19,aw20,aw21,aw22,aw23
#define G3  aw24,aw25,aw26,aw27,aw28,aw29,aw30,aw31
#define G4  aw32,aw33,aw34,aw35,aw36,aw37,aw38,aw39
#define G5  aw40,aw41,aw42,aw43,aw44,aw45,aw46,aw47
#define G6  aw48,aw49,aw50,aw51,aw52,aw53,aw54,aw55
#define G7  aw56,aw57,aw58,aw59,aw60,aw61,aw62,aw63
#define G8  aw64,aw65,aw66,aw67,aw68,aw69,aw70,aw71
#define G9  aw72,aw73,aw74,aw75,aw76,aw77,aw78,aw79
#define G10 aw80,aw81,aw82,aw83,aw84,aw85,aw86,aw87
#define G11 aw88,aw89,aw90,aw91,aw92,aw93,aw94,aw95
#define G12 aw96,aw97,aw98,aw99,aw100,aw101,aw102,aw103
#define G13 aw104,aw105,aw106,aw107,aw108,aw109,aw110,aw111
#define G14 aw112,aw113,aw114,aw115,aw116,aw117,aw118,aw119
#define G15 aw120,aw121,aw122,aw123,aw124,aw125,aw126,aw127
#define G16 aw128,aw129,aw130,aw131,aw132,aw133,aw134,aw135
#define G17 aw136,aw137,aw138,aw139,aw140,aw141,aw142,aw143
#define G18 aw144,aw145,aw146,aw147,aw148,aw149,aw150,aw151
#define G19 aw152,aw153,aw154,aw155,aw156,aw157,aw158,aw159
#define G20 aw160,aw161,aw162,aw163,aw164,aw165,aw166,aw167
#define G21 aw168,aw169,aw170,aw171,aw172,aw173,aw174,aw175
#define G22 aw176,aw177,aw178,aw179,aw180,aw181,aw182,aw183
#define G23 aw184,aw185,aw186,aw187,aw188,aw189,aw190,aw191
#define G24 aw192,aw193,aw194,aw195,aw196,aw197,aw198,aw199

#define XP(M, ...) M(__VA_ARGS__)
#define LW(n) { unsigned t_ = *wp; wp += 400; \
  asm volatile("v_accvgpr_write_b32 %0, %1" : "=a"(n) : "v"(t_)); }
#define LW8(n0,n1,n2,n3,n4,n5,n6,n7) LW(n0) LW(n1) LW(n2) LW(n3) LW(n4) LW(n5) LW(n6) LW(n7)
#define RDW(t, n) asm volatile("v_accvgpr_read_b32 %0, %1" : "=v"(t) : "a"(n));
#define FMALO(acc, w, h) asm volatile( \
  "v_pk_fma_f16 %0, %1, %2, %0 op_sel:[0,0,0] op_sel_hi:[1,0,1]" : "+v"(acc) : "v"(w), "v"(h));
#define FMAHI(acc, w, h) asm volatile( \
  "v_pk_fma_f16 %0, %1, %2, %0 op_sel:[0,1,0] op_sel_hi:[1,1,1]" : "+v"(acc) : "v"(w), "v"(h));
#define QB8(i, n0,n1,n2,n3,n4,n5,n6,n7) { \
  uint4 hv = H[i]; unsigned t_; \
  RDW(t_, n0) FMALO(a0, t_, hv.x) \
  RDW(t_, n1) FMAHI(a1, t_, hv.x) \
  RDW(t_, n2) FMALO(a2, t_, hv.y) \
  RDW(t_, n3) FMAHI(a3, t_, hv.y) \
  RDW(t_, n4) FMALO(a0, t_, hv.z) \
  RDW(t_, n5) FMAHI(a1, t_, hv.z) \
  RDW(t_, n6) FMALO(a2, t_, hv.w) \
  RDW(t_, n7) FMAHI(a3, t_, hv.w) }

__global__ __launch_bounds__(448) void lstm_enc(
    const u16* __restrict__ gates, const unsigned* __restrict__ Wt2,
    const float* __restrict__ Wenc, const float* __restrict__ b_enc,
    const float* __restrict__ emb, const float* __restrict__ W1,
    const float* __restrict__ b1, const float* __restrict__ noise,
    float* __restrict__ p1) {
  __shared__ __attribute__((aligned(16))) __half sh_h[208];
  __shared__ __attribute__((aligned(16))) float sh_hf[HID];
  __shared__ float sh_g[G4H];
  __shared__ __attribute__((aligned(16))) float sh_ze[LATENT];
  __shared__ float sh_zq[LATENT];
  __shared__ float sh_rd[448];
  __shared__ int sh_ri[448];
  const int r = threadIdx.x;
  const int b = blockIdx.x;
  const bool active = (r < 400);

  unsigned G0; unsigned G1; unsigned G2; unsigned G3; unsigned G4;
  unsigned G5; unsigned G6; unsigned G7; unsigned G8; unsigned G9;
  unsigned G10; unsigned G11; unsigned G12; unsigned G13; unsigned G14;
  unsigned G15; unsigned G16; unsigned G17; unsigned G18; unsigned G19;
  unsigned G20; unsigned G21; unsigned G22; unsigned G23; unsigned G24;

  if (active) {
    const unsigned* wp = Wt2 + r;
    XP(LW8, G0)  XP(LW8, G1)  XP(LW8, G2)  XP(LW8, G3)  XP(LW8, G4)
    XP(LW8, G5)  XP(LW8, G6)  XP(LW8, G7)  XP(LW8, G8)  XP(LW8, G9)
    XP(LW8, G10) XP(LW8, G11) XP(LW8, G12) XP(LW8, G13) XP(LW8, G14)
    XP(LW8, G15) XP(LW8, G16) XP(LW8, G17) XP(LW8, G18) XP(LW8, G19)
    XP(LW8, G20) XP(LW8, G21) XP(LW8, G22) XP(LW8, G23) XP(LW8, G24)
  }
  if (r < 208) sh_h[r] = __float2half(0.f);
  float c = 0.f;
  float gvA = 0.f, gvB = 0.f;
  if (active) {
    gvA = b2f(gates[(size_t)(b * TLEN) * LDG + r]);
    gvB = b2f(gates[(size_t)(b * TLEN) * LDG + r + 400]);
  }
  __syncthreads();

  for (int t = 0; t < TLEN; ++t) {
    float gvA_n = 0.f, gvB_n = 0.f;
    if (active && t + 1 < TLEN) {
      gvA_n = b2f(gates[(size_t)(b * TLEN + t + 1) * LDG + r]);
      gvB_n = b2f(gates[(size_t)(b * TLEN + t + 1) * LDG + r + 400]);
    }

    if (active) {
      unsigned a0 = 0, a1 = 0, a2 = 0, a3 = 0;
      const uint4* H = (const uint4*)sh_h;
      XP(QB8, 0,  G0)  XP(QB8, 1,  G1)  XP(QB8, 2,  G2)  XP(QB8, 3,  G3)
      XP(QB8, 4,  G4)  XP(QB8, 5,  G5)  XP(QB8, 6,  G6)  XP(QB8, 7,  G7)
      XP(QB8, 8,  G8)  XP(QB8, 9,  G9)  XP(QB8, 10, G10) XP(QB8, 11, G11)
      XP(QB8, 12, G12) XP(QB8, 13, G13) XP(QB8, 14, G14) XP(QB8, 15, G15)
      XP(QB8, 16, G16) XP(QB8, 17, G17) XP(QB8, 18, G18) XP(QB8, 19, G19)
      XP(QB8, 20, G20) XP(QB8, 21, G21) XP(QB8, 22, G22) XP(QB8, 23, G23)
      XP(QB8, 24, G24)
      __half2 s = __hadd2(__hadd2(__builtin_bit_cast(__half2, a0), __builtin_bit_cast(__half2, a1)),
                          __hadd2(__builtin_bit_cast(__half2, a2), __builtin_bit_cast(__half2, a3)));
      sh_g[r] = gvA + __low2float(s);
      sh_g[r + 400] = gvB + __high2float(s);
    }
    __syncthreads();  // gates visible; all sh_h reads complete
    if (r < HID) {
      float gi = sh_g[r], gf = sh_g[HID + r], gg = sh_g[2 * HID + r], go = sh_g[3 * HID + r];
      c = sigf(gf) * c + sigf(gi) * tanh_fast(gg);
      float h = sigf(go) * tanh_fast(c);
      sh_h[r] = __float2half(h);
      sh_hf[r] = h;
    }
    __syncthreads();  // new h visible
    gvA = gvA_n; gvB = gvB_n;
  }

  // encoder: z_e = h @ Wenc^T + b_enc
  if (r < LATENT) {
    float z = b_enc[r];
#pragma unroll 4
    for (int k = 0; k < HID; ++k) z = fmaf(Wenc[(size_t)r * HID + k], sh_hf[k], z);
    sh_ze[r] = z;
  }
  __syncthreads();

  // VQ: argmin_k ||e_k||^2 - 2 z_e . e_k
  float best = INFINITY; int bi = 0;
  for (int k = r; k < NCODES; k += 448) {
    float d = 0.f;
#pragma unroll
    for (int q = 0; q < LATENT / 4; ++q) {
      float4 e = *(const float4*)&emb[(size_t)k * LATENT + q * 4];
      float4 z = *(const float4*)&sh_ze[q * 4];
      d += e.x * (e.x - 2.f * z.x) + e.y * (e.y - 2.f * z.y)
         + e.z * (e.z - 2.f * z.z) + e.w * (e.w - 2.f * z.w);
    }
    if (d < best) { best = d; bi = k; }
  }
  sh_rd[r] = best; sh_ri[r] = bi;
  __syncthreads();
  for (int s = 256; s > 0; s >>= 1) {
    if (r < s && r + s < 448) {
      float od = sh_rd[r + s]; int oi = sh_ri[r + s];
      if (od < sh_rd[r] || (od == sh_rd[r] && oi < sh_ri[r])) { sh_rd[r] = od; sh_ri[r] = oi; }
    }
    __syncthreads();
  }
  const int kmin = sh_ri[0];
  if (r < LATENT) sh_zq[r] = emb[(size_t)kmin * LATENT + r];
  __syncthreads();

  // p1[b][j] = b1 + W1[:,0:128].zq + W1[:,1664:2432].noise  (pad cols 200..255 = 0)
  if (r < 256) {
    float v = 0.f;
    if (r < HID) {
      v = b1[r];
      const float* wrow = W1 + (size_t)r * 2432;
#pragma unroll 4
      for (int d = 0; d < LATENT; ++d) v = fmaf(wrow[d], sh_zq[d], v);
      const float* nz = noise + (size_t)b * DIN;
#pragma unroll 4
      for (int d = 0; d < DIN; ++d) v = fmaf(wrow[1664 + d], nz[d], v);
    }
    p1[b * 256 + r] = v;
  }
}

// ---------------- host ----------------
extern "C" void kernel_launch(void* const* d_in, const int* in_sizes, int n_in,
                              void* d_out, int out_size, void* d_ws, size_t ws_size,
                              hipStream_t stream) {
  const float* x     = (const float*)d_in[0];
  const float* cond  = (const float*)d_in[1];
  const float* noise = (const float*)d_in[2];
  const float* W_ih  = (const float*)d_in[3];
  const float* W_hh  = (const float*)d_in[4];
  const float* b_ih  = (const float*)d_in[5];
  const float* b_hh  = (const float*)d_in[6];
  const float* W_enc = (const float*)d_in[7];
  const float* b_enc = (const float*)d_in[8];
  const float* emb   = (const float*)d_in[9];
  const float* W1    = (const float*)d_in[10];
  const float* b1    = (const float*)d_in[11];
  const float* W2    = (const float*)d_in[12];
  const float* b2    = (const float*)d_in[13];
  const float* W3    = (const float*)d_in[14];
  const float* b3    = (const float*)d_in[15];

  char* ws = (char*)d_ws;
  size_t off = 0;
  auto alloc = [&](size_t bytes) -> void* {
    void* p = ws + off; off += (bytes + 255) & ~(size_t)255; return p;
  };
  u16*      W_ihb = (u16*)alloc((size_t)896 * 768 * 2);
  u16*      W1cb  = (u16*)alloc((size_t)256 * 1536 * 2);
  u16*      W2b   = (u16*)alloc((size_t)512 * 256 * 2);
  u16*      W3b   = (u16*)alloc((size_t)768 * 512 * 2);
  float*    b2p   = (float*)alloc(512 * 4);
  unsigned* Wt2   = (unsigned*)alloc((size_t)200 * 400 * 4);
  float*    biasc = (float*)alloc(LDG * 4);
  u16*      gates = (u16*)alloc((size_t)MROWS * LDG * 2);
  float*    p1    = (float*)alloc(256 * 256 * 4);
  u16*      h1    = (u16*)alloc((size_t)MROWS * LDH1 * 2);
  u16*      h2    = (u16*)alloc((size_t)MROWS * LDH2 * 2);

  cvt_pad<<<dim3((896 * 768 + 255) / 256), 256, 0, stream>>>(W_ih, W_ihb, 800, 768, 768, 0, 896, 768);
  cvt_pad<<<dim3((256 * 1536 + 255) / 256), 256, 0, stream>>>(W1, W1cb, 200, 1536, 2432, 128, 256, 1536);
  cvt_pad<<<dim3((512 * 256 + 255) / 256), 256, 0, stream>>>(W2, W2b, 400, 200, 200, 0, 512, 256);
  cvt_pad<<<dim3((768 * 512 + 255) / 256), 256, 0, stream>>>(W3, W3b, 768, 400, 400, 0, 768, 512);
  pad_f32<<<dim3(2), 256, 0, stream>>>(b2, b2p, 400, 512);
  pack_whh2<<<dim3((200 * 400 + 255) / 256), 256, 0, stream>>>(W_hh, Wt2, b_ih, b_hh, biasc);

  // gates = x @ W_ih^T + (b_ih + b_hh), bf16 out, ld 896
  gemm_bf16<true, EPI_GATES><<<dim3(LDG / 128, MROWS / 128), 256, 0, stream>>>(
      x, W_ihb, gates, 768, LDG, biasc);

  // LSTM scan + encoder + VQ + p1
  lstm_enc<<<dim3(NB), 448, 0, stream>>>(gates, Wt2, W_enc, b_enc,
                                         emb, W1, b1, noise, p1);

  // h1 = relu(cond @ W1c^T + p1[b])
  gemm_bf16<true, EPI_H1><<<dim3(LDH1 / 128, MROWS / 128), 256, 0, stream>>>(
      cond, W1cb, h1, DCOND, LDH1, p1);
  // h2 = relu(h1 @ W2^T + b2)
  gemm_bf16<false, EPI_H2><<<dim3(LDH2 / 128, MROWS / 128), 256, 0, stream>>>(
      h1, W2b, h2, LDH1, LDH2, b2p);
  // out = sigmoid(h2 @ W3^T + b3)
  gemm_bf16<false, EPI_OUT><<<dim3(NOUT / 128, MROWS / 128), 256, 0, stream>>>(
      h2, W3b, (float*)d_out, LDH2, NOUT, b3);
}

// Round 8
// 709.208 us; speedup vs baseline: 1.1026x; 1.1026x over previous
//
#include <hip/hip_runtime.h>
#include <math.h>

typedef unsigned short u16;
typedef u16 u16x8 __attribute__((ext_vector_type(8)));
typedef __bf16 bf16x8 __attribute__((ext_vector_type(8)));
typedef float f32x4 __attribute__((ext_vector_type(4)));
typedef float f32x2 __attribute__((ext_vector_type(2)));

#define HID 200
#define G4H 800
#define TLEN 128
#define LATENT 128
#define NCODES 1024
#define DIN 768
#define DCOND 1536
#define NB 256
#define MROWS (NB * TLEN)
#define LDG 896
#define LDH1 256
#define LDH2 512
#define NOUT 768

__device__ __forceinline__ u16 f2b(float f) {
  union { float f; unsigned u; } v; v.f = f;
  unsigned r = v.u + 0x7fffu + ((v.u >> 16) & 1u);
  return (u16)(r >> 16);
}
__device__ __forceinline__ float b2f(u16 h) {
  union { unsigned u; float f; } v; v.u = ((unsigned)h) << 16;
  return v.f;
}
__device__ __forceinline__ float sigf(float x) { return 1.f / (1.f + __expf(-x)); }
__device__ __forceinline__ float tanh_fast(float x) {
  return 1.f - 2.f / (__expf(2.f * x) + 1.f);
}

// manual fp8 e4m3fn encode (OCP; matches gfx950 v_cvt_pk_f32_fp8 decode)
__device__ __forceinline__ unsigned enc_e4m3(float v) {
  union { float f; unsigned u; } x; x.f = v;
  unsigned s = (x.u >> 31) << 7;
  float a = fabsf(v);
  if (a == 0.f) return s;
  if (a >= 448.f) return s | 0x7E;
  int exp = (int)((x.u >> 23) & 0xFF) - 127;
  unsigned man = (x.u >> 20) & 0x7;
  unsigned rnd = (x.u >> 19) & 1;
  man += rnd;
  if (man > 7) { man = 0; exp += 1; }
  int be = exp + 7;
  if (be >= 16) return s | 0x7E;
  if (be <= 0) {
    int q = (int)(a * 512.f + 0.5f);
    if (q > 7) q = 7;
    return s | (unsigned)q;
  }
  return s | ((unsigned)be << 4) | man;
}

// async global->LDS, 16B per lane
__device__ __forceinline__ void gl16(const void* g, void* l) {
  __builtin_amdgcn_global_load_lds(
      (const __attribute__((address_space(1))) void*)g,
      (__attribute__((address_space(3))) void*)l, 16, 0, 0);
}

__device__ __forceinline__ unsigned cvtpk(float a, float b) {
  unsigned r;
  asm("v_cvt_pk_bf16_f32 %0, %1, %2" : "=v"(r) : "v"(a), "v"(b));
  return r;
}

// ---------------- weight convert + pad ----------------
__global__ void cvt_pad(const float* __restrict__ src, u16* __restrict__ dst,
                        int nr, int nc, int lds, int col0, int NRp, int KP) {
  int i = blockIdx.x * blockDim.x + threadIdx.x;
  if (i >= NRp * KP) return;
  int r = i / KP, c = i - r * KP;
  float v = (r < nr && c < nc) ? src[(size_t)r * lds + col0 + c] : 0.f;
  dst[i] = f2b(v);
}

__global__ void pad_f32(const float* __restrict__ src, float* __restrict__ dst,
                        int n, int npad) {
  int i = blockIdx.x * blockDim.x + threadIdx.x;
  if (i < npad) dst[i] = (i < n) ? src[i] : 0.f;
}

// W_hh [800][200] f32 -> Wq[j*400+r] = fp8x4( 16*W[r][2j], 16*W[r+400][2j],
//                                             16*W[r][2j+1], 16*W[r+400][2j+1] )
// biasc[col<896] = b_ih+b_hh (0-padded) for the gates-GEMM epilogue.
__global__ void pack_whh_fp8(const float* __restrict__ Whh, unsigned* __restrict__ Wq,
                             const float* __restrict__ b_ih, const float* __restrict__ b_hh,
                             float* __restrict__ biasc) {
  int i = blockIdx.x * blockDim.x + threadIdx.x;
  if (i < 100 * 400) {
    int j = i / 400, r = i - j * 400;
    int k = 2 * j;
    unsigned b0 = enc_e4m3(16.f * Whh[(size_t)r * HID + k]);
    unsigned b1 = enc_e4m3(16.f * Whh[(size_t)(r + 400) * HID + k]);
    unsigned b2 = enc_e4m3(16.f * Whh[(size_t)r * HID + k + 1]);
    unsigned b3 = enc_e4m3(16.f * Whh[(size_t)(r + 400) * HID + k + 1]);
    Wq[i] = b0 | (b1 << 8) | (b2 << 16) | (b3 << 24);
  }
  if (i < LDG) biasc[i] = (i < G4H) ? (b_ih[i] + b_hh[i]) : 0.f;
}

// ---------------- bf16 MFMA GEMM: C[M,N] = A[M,K] * B[N,K]^T (+epilogue) ----------------
enum { EPI_GATES = 0, EPI_H1 = 1, EPI_H2 = 2, EPI_OUT = 3 };

__device__ __forceinline__ f32x4 mfma16(bf16x8 a, bf16x8 b, f32x4 c) {
  return __builtin_amdgcn_mfma_f32_16x16x32_bf16(a, b, c, 0, 0, 0);
}

template<bool AF32, int EPI>
__global__ __launch_bounds__(256) void gemm_bf16(
    const void* __restrict__ Ap, const u16* __restrict__ Bp,
    void* __restrict__ Cp, int K, int ldc, const float* __restrict__ bias) {
  __shared__ __attribute__((aligned(16))) char AsRaw[AF32 ? 128 * 32 * 4 : 128 * 32 * 2];
  __shared__ __attribute__((aligned(16))) u16 Bs[128 * 32];
  float* Asf = (float*)AsRaw;
  u16* As16 = (u16*)AsRaw;

  const int t = threadIdx.x;
  const int tileN = blockIdx.x * 128;
  const int tileM = blockIdx.y * 128;
  const int l = t & 63;
  const int w = t >> 6;
  const int wr = (w >> 1) * 64;
  const int wc = (w & 1) * 64;
  const int fr = l & 15;
  const int fg = l >> 4;

  const u16* bsrc[2];
  u16* bdst[2];
#pragma unroll
  for (int j = 0; j < 2; ++j) {
    int tb = w * 1024 + j * 4096 + (t & 63) * 16;
    int row = tb >> 6, gd = (tb >> 4) & 3;
    bsrc[j] = Bp + (size_t)(tileN + row) * K + ((gd ^ ((row >> 1) & 3)) << 3);
    bdst[j] = Bs + w * 512 + j * 2048;
  }
  const float* asrcF[4];
  float* adstF[4];
  const u16* asrcH[2];
  u16* adstH[2];
  if constexpr (AF32) {
#pragma unroll
    for (int j = 0; j < 4; ++j) {
      int tb = w * 1024 + j * 4096 + (t & 63) * 16;
      int row = tb >> 7, gd = (tb >> 4) & 7;
      asrcF[j] = (const float*)Ap + (size_t)(tileM + row) * K + ((gd ^ (row & 7)) << 2);
      adstF[j] = Asf + w * 256 + j * 1024;
    }
  } else {
#pragma unroll
    for (int j = 0; j < 2; ++j) {
      int tb = w * 1024 + j * 4096 + (t & 63) * 16;
      int row = tb >> 6, gd = (tb >> 4) & 3;
      asrcH[j] = (const u16*)Ap + (size_t)(tileM + row) * K + ((gd ^ ((row >> 1) & 3)) << 3);
      adstH[j] = As16 + w * 512 + j * 2048;
    }
  }

  f32x4 acc[4][4];
#pragma unroll
  for (int m = 0; m < 4; ++m)
#pragma unroll
    for (int n = 0; n < 4; ++n) {
      f32x4 z = {0.f, 0.f, 0.f, 0.f};
      acc[m][n] = z;
    }

  for (int k0 = 0; k0 < K; k0 += 32) {
#pragma unroll
    for (int j = 0; j < 2; ++j) { gl16(bsrc[j], bdst[j]); bsrc[j] += 32; }
    if constexpr (AF32) {
#pragma unroll
      for (int j = 0; j < 4; ++j) { gl16(asrcF[j], adstF[j]); asrcF[j] += 32; }
    } else {
#pragma unroll
      for (int j = 0; j < 2; ++j) { gl16(asrcH[j], adstH[j]); asrcH[j] += 32; }
    }
    __syncthreads();

    bf16x8 av[4], bv[4];
#pragma unroll
    for (int m = 0; m < 4; ++m) {
      const int row = wr + m * 16 + fr;
      if constexpr (AF32) {
        const int g0 = (2 * fg) ^ (row & 7);
        const int g1 = (2 * fg + 1) ^ (row & 7);
        float4 p0 = *(const float4*)(Asf + row * 32 + g0 * 4);
        float4 p1 = *(const float4*)(Asf + row * 32 + g1 * 4);
        uint4 u;
        u.x = cvtpk(p0.x, p0.y); u.y = cvtpk(p0.z, p0.w);
        u.z = cvtpk(p1.x, p1.y); u.w = cvtpk(p1.z, p1.w);
        av[m] = __builtin_bit_cast(bf16x8, u);
      } else {
        const int g = fg ^ ((row >> 1) & 3);
        av[m] = __builtin_bit_cast(bf16x8, *(const u16x8*)(As16 + row * 32 + g * 8));
      }
    }
#pragma unroll
    for (int n = 0; n < 4; ++n) {
      const int row = wc + n * 16 + fr;
      const int g = fg ^ ((row >> 1) & 3);
      bv[n] = __builtin_bit_cast(bf16x8, *(const u16x8*)(Bs + row * 32 + g * 8));
    }
#pragma unroll
    for (int m = 0; m < 4; ++m)
#pragma unroll
      for (int n = 0; n < 4; ++n)
        acc[m][n] = mfma16(av[m], bv[n], acc[m][n]);
    __syncthreads();
  }

#pragma unroll
  for (int m = 0; m < 4; ++m) {
#pragma unroll
    for (int n = 0; n < 4; ++n) {
      const int gcol = tileN + wc + n * 16 + fr;
      const int growb = tileM + wr + m * 16 + fg * 4;
#pragma unroll
      for (int r = 0; r < 4; ++r) {
        const int grow = growb + r;
        float v = acc[m][n][r];
        if constexpr (EPI == EPI_GATES) {
          v += bias[gcol];   // b_ih + b_hh folded here
          ((u16*)Cp)[(size_t)grow * ldc + gcol] = f2b(v);
        } else if constexpr (EPI == EPI_H1) {
          v += bias[(grow >> 7) * 256 + gcol];
          v = fmaxf(v, 0.f);
          ((u16*)Cp)[(size_t)grow * ldc + gcol] = f2b(v);
        } else if constexpr (EPI == EPI_H2) {
          v += bias[gcol];
          v = fmaxf(v, 0.f);
          ((u16*)Cp)[(size_t)grow * ldc + gcol] = f2b(v);
        } else {
          v += bias[gcol];
          ((float*)Cp)[(size_t)grow * ldc + gcol] = sigf(v);
        }
      }
    }
  }
}

// ---------------- fused LSTM scan + encoder + VQ + p1 ----------------
// 448 threads (7 waves), one block per batch element. Thread r<400 owns gate
// rows {r, r+400} for all 200 k as 100 fp8x4 dwords (x16 scale) in plain VGPRs.
// 100 + ~20 live state fits the allocator's revealed 128-VGPR grant at 7 waves
// (R3/R7 evidence); no attrs, no AGPR read tax (R7 lesson). Bias folded into
// the gates-GEMM epilogue. fp8 numerics validated in R5 (absmax 0.0059).
__global__ __launch_bounds__(448) void lstm_enc(
    const u16* __restrict__ gates, const unsigned* __restrict__ Wq,
    const float* __restrict__ Wenc, const float* __restrict__ b_enc,
    const float* __restrict__ emb, const float* __restrict__ W1,
    const float* __restrict__ b1, const float* __restrict__ noise,
    float* __restrict__ p1) {
  __shared__ __attribute__((aligned(16))) float sh_hf[HID];
  __shared__ float sh_g[G4H];
  __shared__ __attribute__((aligned(16))) float sh_ze[LATENT];
  __shared__ float sh_zq[LATENT];
  __shared__ float sh_rd[448];
  __shared__ int sh_ri[448];
  const int r = threadIdx.x;
  const int b = blockIdx.x;
  const bool active = (r < 400);

  unsigned wv[100];
  if (active) {
    const unsigned* wp = Wq + r;
#pragma unroll
    for (int j = 0; j < 100; ++j) { wv[j] = *wp; wp += 400; }
  }
  if (r < HID) sh_hf[r] = 0.f;
  float c = 0.f;
  const u16* gp = gates + (size_t)b * TLEN * LDG + r;
  float gvA = 0.f, gvB = 0.f;
  if (active) { gvA = b2f(gp[0]); gvB = b2f(gp[400]); }
  __syncthreads();

  for (int t = 0; t < TLEN; ++t) {
    gp += LDG;
    float gvA_n = 0.f, gvB_n = 0.f;
    if (active && t + 1 < TLEN) { gvA_n = b2f(gp[0]); gvB_n = b2f(gp[400]); }

    if (active) {
      float sA = 0.f, sB = 0.f;
      const float4* H = (const float4*)sh_hf;
#pragma unroll
      for (int q = 0; q < 50; ++q) {
        float4 h4 = H[q];
        unsigned w0 = wv[2 * q], w1 = wv[2 * q + 1];
        f32x2 lo0 = __builtin_amdgcn_cvt_pk_f32_fp8(w0, 0);  // (A_k, B_k)
        f32x2 hi0 = __builtin_amdgcn_cvt_pk_f32_fp8(w0, 1);  // (A_k1, B_k1)
        sA = fmaf(lo0.x, h4.x, sA); sB = fmaf(lo0.y, h4.x, sB);
        sA = fmaf(hi0.x, h4.y, sA); sB = fmaf(hi0.y, h4.y, sB);
        f32x2 lo1 = __builtin_amdgcn_cvt_pk_f32_fp8(w1, 0);
        f32x2 hi1 = __builtin_amdgcn_cvt_pk_f32_fp8(w1, 1);
        sA = fmaf(lo1.x, h4.z, sA); sB = fmaf(lo1.y, h4.z, sB);
        sA = fmaf(hi1.x, h4.w, sA); sB = fmaf(hi1.y, h4.w, sB);
      }
      sh_g[r] = gvA + sA * 0.0625f;
      sh_g[r + 400] = gvB + sB * 0.0625f;
    }
    __syncthreads();  // gates visible; all sh_hf reads complete
    if (r < HID) {
      float gi = sh_g[r], gf = sh_g[HID + r], gg = sh_g[2 * HID + r], go = sh_g[3 * HID + r];
      c = sigf(gf) * c + sigf(gi) * tanh_fast(gg);
      sh_hf[r] = sigf(go) * tanh_fast(c);
    }
    __syncthreads();  // new h visible
    gvA = gvA_n; gvB = gvB_n;
  }

  // encoder: z_e = h @ Wenc^T + b_enc
  if (r < LATENT) {
    float z = b_enc[r];
#pragma unroll 4
    for (int k = 0; k < HID; ++k) z = fmaf(Wenc[(size_t)r * HID + k], sh_hf[k], z);
    sh_ze[r] = z;
  }
  __syncthreads();

  // VQ: argmin_k ||e_k||^2 - 2 z_e . e_k
  float best = INFINITY; int bi = 0;
  for (int k = r; k < NCODES; k += 448) {
    float d = 0.f;
#pragma unroll
    for (int q = 0; q < LATENT / 4; ++q) {
      float4 e = *(const float4*)&emb[(size_t)k * LATENT + q * 4];
      float4 z = *(const float4*)&sh_ze[q * 4];
      d += e.x * (e.x - 2.f * z.x) + e.y * (e.y - 2.f * z.y)
         + e.z * (e.z - 2.f * z.z) + e.w * (e.w - 2.f * z.w);
    }
    if (d < best) { best = d; bi = k; }
  }
  sh_rd[r] = best; sh_ri[r] = bi;
  __syncthreads();
  for (int s = 256; s > 0; s >>= 1) {
    if (r < s && r + s < 448) {
      float od = sh_rd[r + s]; int oi = sh_ri[r + s];
      if (od < sh_rd[r] || (od == sh_rd[r] && oi < sh_ri[r])) { sh_rd[r] = od; sh_ri[r] = oi; }
    }
    __syncthreads();
  }
  const int kmin = sh_ri[0];
  if (r < LATENT) sh_zq[r] = emb[(size_t)kmin * LATENT + r];
  __syncthreads();

  // p1[b][j] = b1 + W1[:,0:128].zq + W1[:,1664:2432].noise  (pad cols 200..255 = 0)
  if (r < 256) {
    float v = 0.f;
    if (r < HID) {
      v = b1[r];
      const float* wrow = W1 + (size_t)r * 2432;
#pragma unroll 4
      for (int d = 0; d < LATENT; ++d) v = fmaf(wrow[d], sh_zq[d], v);
      const float* nz = noise + (size_t)b * DIN;
#pragma unroll 4
      for (int d = 0; d < DIN; ++d) v = fmaf(wrow[1664 + d], nz[d], v);
    }
    p1[b * 256 + r] = v;
  }
}

// ---------------- host ----------------
extern "C" void kernel_launch(void* const* d_in, const int* in_sizes, int n_in,
                              void* d_out, int out_size, void* d_ws, size_t ws_size,
                              hipStream_t stream) {
  const float* x     = (const float*)d_in[0];
  const float* cond  = (const float*)d_in[1];
  const float* noise = (const float*)d_in[2];
  const float* W_ih  = (const float*)d_in[3];
  const float* W_hh  = (const float*)d_in[4];
  const float* b_ih  = (const float*)d_in[5];
  const float* b_hh  = (const float*)d_in[6];
  const float* W_enc = (const float*)d_in[7];
  const float* b_enc = (const float*)d_in[8];
  const float* emb   = (const float*)d_in[9];
  const float* W1    = (const float*)d_in[10];
  const float* b1    = (const float*)d_in[11];
  const float* W2    = (const float*)d_in[12];
  const float* b2    = (const float*)d_in[13];
  const float* W3    = (const float*)d_in[14];
  const float* b3    = (const float*)d_in[15];

  char* ws = (char*)d_ws;
  size_t off = 0;
  auto alloc = [&](size_t bytes) -> void* {
    void* p = ws + off; off += (bytes + 255) & ~(size_t)255; return p;
  };
  u16*      W_ihb = (u16*)alloc((size_t)896 * 768 * 2);
  u16*      W1cb  = (u16*)alloc((size_t)256 * 1536 * 2);
  u16*      W2b   = (u16*)alloc((size_t)512 * 256 * 2);
  u16*      W3b   = (u16*)alloc((size_t)768 * 512 * 2);
  float*    b2p   = (float*)alloc(512 * 4);
  unsigned* Wq    = (unsigned*)alloc((size_t)100 * 400 * 4);
  float*    biasc = (float*)alloc(LDG * 4);
  u16*      gates = (u16*)alloc((size_t)MROWS * LDG * 2);
  float*    p1    = (float*)alloc(256 * 256 * 4);
  u16*      h1    = (u16*)alloc((size_t)MROWS * LDH1 * 2);
  u16*      h2    = (u16*)alloc((size_t)MROWS * LDH2 * 2);

  cvt_pad<<<dim3((896 * 768 + 255) / 256), 256, 0, stream>>>(W_ih, W_ihb, 800, 768, 768, 0, 896, 768);
  cvt_pad<<<dim3((256 * 1536 + 255) / 256), 256, 0, stream>>>(W1, W1cb, 200, 1536, 2432, 128, 256, 1536);
  cvt_pad<<<dim3((512 * 256 + 255) / 256), 256, 0, stream>>>(W2, W2b, 400, 200, 200, 0, 512, 256);
  cvt_pad<<<dim3((768 * 512 + 255) / 256), 256, 0, stream>>>(W3, W3b, 768, 400, 400, 0, 768, 512);
  pad_f32<<<dim3(2), 256, 0, stream>>>(b2, b2p, 400, 512);
  pack_whh_fp8<<<dim3((100 * 400 + 255) / 256), 256, 0, stream>>>(W_hh, Wq, b_ih, b_hh, biasc);

  // gates = x @ W_ih^T + (b_ih + b_hh), bf16 out, ld 896
  gemm_bf16<true, EPI_GATES><<<dim3(LDG / 128, MROWS / 128), 256, 0, stream>>>(
      x, W_ihb, gates, 768, LDG, biasc);

  // LSTM scan + encoder + VQ + p1
  lstm_enc<<<dim3(NB), 448, 0, stream>>>(gates, Wq, W_enc, b_enc,
                                         emb, W1, b1, noise, p1);

  // h1 = relu(cond @ W1c^T + p1[b])
  gemm_bf16<true, EPI_H1><<<dim3(LDH1 / 128, MROWS / 128), 256, 0, stream>>>(
      cond, W1cb, h1, DCOND, LDH1, p1);
  // h2 = relu(h1 @ W2^T + b2)
  gemm_bf16<false, EPI_H2><<<dim3(LDH2 / 128, MROWS / 128), 256, 0, stream>>>(
      h1, W2b, h2, LDH1, LDH2, b2p);
  // out = sigmoid(h2 @ W3^T + b3)
  gemm_bf16<false, EPI_OUT><<<dim3(NOUT / 128, MROWS / 128), 256, 0, stream>>>(
      h2, W3b, (float*)d_out, LDH2, NOUT, b3);
}

// Round 9
// 552.553 us; speedup vs baseline: 1.4152x; 1.2835x over previous
//
#include <hip/hip_runtime.h>
#include <math.h>

typedef unsigned short u16;
typedef u16 u16x8 __attribute__((ext_vector_type(8)));
typedef __bf16 bf16x8 __attribute__((ext_vector_type(8)));
typedef float f32x4 __attribute__((ext_vector_type(4)));

#define HID 200
#define G4H 800
#define TLEN 128
#define LATENT 128
#define NCODES 1024
#define DIN 768
#define DCOND 1536
#define NB 256
#define MROWS (NB * TLEN)
#define LDG 896
#define LDH1 256
#define LDH2 512
#define NOUT 768

#define WSCL 400.0f
#define HSCL 127.0f
#define ISCL (1.0f / (WSCL * HSCL))
#define W4_DWORDS (12 * 800 * 4)   // k 0..191 in LDS, i8-packed
#define W4_BYTES (W4_DWORDS * 4)   // 153600

__device__ __forceinline__ u16 f2b(float f) {
  union { float f; unsigned u; } v; v.f = f;
  unsigned r = v.u + 0x7fffu + ((v.u >> 16) & 1u);
  return (u16)(r >> 16);
}
__device__ __forceinline__ float b2f(u16 h) {
  union { unsigned u; float f; } v; v.u = ((unsigned)h) << 16;
  return v.f;
}
__device__ __forceinline__ float sigf(float x) { return 1.f / (1.f + __expf(-x)); }
__device__ __forceinline__ float tanh_fast(float x) {
  return 1.f - 2.f / (__expf(2.f * x) + 1.f);
}

__device__ __forceinline__ int dot4(unsigned a, unsigned b, int c) {
#if __has_builtin(__builtin_amdgcn_sdot4)
  return __builtin_amdgcn_sdot4((int)a, (int)b, c, false);
#else
  int s = c;
  s += (int)(signed char)(a) * (int)(signed char)(b);
  s += (int)(signed char)(a >> 8) * (int)(signed char)(b >> 8);
  s += (int)(signed char)(a >> 16) * (int)(signed char)(b >> 16);
  s += (int)(signed char)(a >> 24) * (int)(signed char)(b >> 24);
  return s;
#endif
}

// async global->LDS, 16B per lane
__device__ __forceinline__ void gl16(const void* g, void* l) {
  __builtin_amdgcn_global_load_lds(
      (const __attribute__((address_space(1))) void*)g,
      (__attribute__((address_space(3))) void*)l, 16, 0, 0);
}

__device__ __forceinline__ unsigned cvtpk(float a, float b) {
  unsigned r;
  asm("v_cvt_pk_bf16_f32 %0, %1, %2" : "=v"(r) : "v"(a), "v"(b));
  return r;
}

// ---------------- weight convert + pad ----------------
__global__ void cvt_pad(const float* __restrict__ src, u16* __restrict__ dst,
                        int nr, int nc, int lds, int col0, int NRp, int KP) {
  int i = blockIdx.x * blockDim.x + threadIdx.x;
  if (i >= NRp * KP) return;
  int r = i / KP, c = i - r * KP;
  float v = (r < nr && c < nc) ? src[(size_t)r * lds + col0 + c] : 0.f;
  dst[i] = f2b(v);
}

__global__ void pad_f32(const float* __restrict__ src, float* __restrict__ dst,
                        int n, int npad) {
  int i = blockIdx.x * blockDim.x + threadIdx.x;
  if (i < npad) dst[i] = (i < n) ? src[i] : 0.f;
}

// W_hh [800][200] f32 -> i8 (x400 scale):
//   k 0..191  -> W4 dword index (dw4>>2)*3200 + row*4 + (dw4&3)  (uint4 = [jb*800+row])
//   k 192..199-> Wreg[r*4 + {0,1}(row<400) / {2,3}(row>=400)]
// biasc[col<896] = b_ih+b_hh (0-padded) for the gates-GEMM epilogue.
__global__ void pack_whh_i8(const float* __restrict__ Whh, unsigned* __restrict__ W4,
                            unsigned* __restrict__ Wreg,
                            const float* __restrict__ b_ih, const float* __restrict__ b_hh,
                            float* __restrict__ biasc) {
  int i = blockIdx.x * blockDim.x + threadIdx.x;
  if (i < 800 * 50) {
    int row = i / 50, dw = i - row * 50;
    unsigned d = 0;
#pragma unroll
    for (int e = 0; e < 4; ++e) {
      int k = dw * 4 + e;
      float w = Whh[(size_t)row * HID + k] * WSCL;
      int q = (int)lrintf(w);
      q = q > 127 ? 127 : (q < -127 ? -127 : q);
      d |= ((unsigned)(q & 0xFF)) << (8 * e);
    }
    if (dw < 48) {
      W4[(dw >> 2) * 3200 + row * 4 + (dw & 3)] = d;
    } else {
      int r = (row < 400) ? row : row - 400;
      int base = (row < 400) ? 0 : 2;
      Wreg[r * 4 + base + (dw - 48)] = d;
    }
  }
  if (i < LDG) biasc[i] = (i < G4H) ? (b_ih[i] + b_hh[i]) : 0.f;
}

// ---------------- bf16 MFMA GEMM: C[M,N] = A[M,K] * B[N,K]^T (+epilogue) ----------------
enum { EPI_GATES = 0, EPI_H1 = 1, EPI_H2 = 2, EPI_OUT = 3 };

__device__ __forceinline__ f32x4 mfma16(bf16x8 a, bf16x8 b, f32x4 c) {
  return __builtin_amdgcn_mfma_f32_16x16x32_bf16(a, b, c, 0, 0, 0);
}

template<bool AF32, int EPI>
__global__ __launch_bounds__(256) void gemm_bf16(
    const void* __restrict__ Ap, const u16* __restrict__ Bp,
    void* __restrict__ Cp, int K, int ldc, const float* __restrict__ bias) {
  __shared__ __attribute__((aligned(16))) char AsRaw[AF32 ? 128 * 32 * 4 : 128 * 32 * 2];
  __shared__ __attribute__((aligned(16))) u16 Bs[128 * 32];
  float* Asf = (float*)AsRaw;
  u16* As16 = (u16*)AsRaw;

  const int t = threadIdx.x;
  const int tileN = blockIdx.x * 128;
  const int tileM = blockIdx.y * 128;
  const int l = t & 63;
  const int w = t >> 6;
  const int wr = (w >> 1) * 64;
  const int wc = (w & 1) * 64;
  const int fr = l & 15;
  const int fg = l >> 4;

  const u16* bsrc[2];
  u16* bdst[2];
#pragma unroll
  for (int j = 0; j < 2; ++j) {
    int tb = w * 1024 + j * 4096 + (t & 63) * 16;
    int row = tb >> 6, gd = (tb >> 4) & 3;
    bsrc[j] = Bp + (size_t)(tileN + row) * K + ((gd ^ ((row >> 1) & 3)) << 3);
    bdst[j] = Bs + w * 512 + j * 2048;
  }
  const float* asrcF[4];
  float* adstF[4];
  const u16* asrcH[2];
  u16* adstH[2];
  if constexpr (AF32) {
#pragma unroll
    for (int j = 0; j < 4; ++j) {
      int tb = w * 1024 + j * 4096 + (t & 63) * 16;
      int row = tb >> 7, gd = (tb >> 4) & 7;
      asrcF[j] = (const float*)Ap + (size_t)(tileM + row) * K + ((gd ^ (row & 7)) << 2);
      adstF[j] = Asf + w * 256 + j * 1024;
    }
  } else {
#pragma unroll
    for (int j = 0; j < 2; ++j) {
      int tb = w * 1024 + j * 4096 + (t & 63) * 16;
      int row = tb >> 6, gd = (tb >> 4) & 3;
      asrcH[j] = (const u16*)Ap + (size_t)(tileM + row) * K + ((gd ^ ((row >> 1) & 3)) << 3);
      adstH[j] = As16 + w * 512 + j * 2048;
    }
  }

  f32x4 acc[4][4];
#pragma unroll
  for (int m = 0; m < 4; ++m)
#pragma unroll
    for (int n = 0; n < 4; ++n) {
      f32x4 z = {0.f, 0.f, 0.f, 0.f};
      acc[m][n] = z;
    }

  for (int k0 = 0; k0 < K; k0 += 32) {
#pragma unroll
    for (int j = 0; j < 2; ++j) { gl16(bsrc[j], bdst[j]); bsrc[j] += 32; }
    if constexpr (AF32) {
#pragma unroll
      for (int j = 0; j < 4; ++j) { gl16(asrcF[j], adstF[j]); asrcF[j] += 32; }
    } else {
#pragma unroll
      for (int j = 0; j < 2; ++j) { gl16(asrcH[j], adstH[j]); asrcH[j] += 32; }
    }
    __syncthreads();

    bf16x8 av[4], bv[4];
#pragma unroll
    for (int m = 0; m < 4; ++m) {
      const int row = wr + m * 16 + fr;
      if constexpr (AF32) {
        const int g0 = (2 * fg) ^ (row & 7);
        const int g1 = (2 * fg + 1) ^ (row & 7);
        float4 p0 = *(const float4*)(Asf + row * 32 + g0 * 4);
        float4 p1 = *(const float4*)(Asf + row * 32 + g1 * 4);
        uint4 u;
        u.x = cvtpk(p0.x, p0.y); u.y = cvtpk(p0.z, p0.w);
        u.z = cvtpk(p1.x, p1.y); u.w = cvtpk(p1.z, p1.w);
        av[m] = __builtin_bit_cast(bf16x8, u);
      } else {
        const int g = fg ^ ((row >> 1) & 3);
        av[m] = __builtin_bit_cast(bf16x8, *(const u16x8*)(As16 + row * 32 + g * 8));
      }
    }
#pragma unroll
    for (int n = 0; n < 4; ++n) {
      const int row = wc + n * 16 + fr;
      const int g = fg ^ ((row >> 1) & 3);
      bv[n] = __builtin_bit_cast(bf16x8, *(const u16x8*)(Bs + row * 32 + g * 8));
    }
#pragma unroll
    for (int m = 0; m < 4; ++m)
#pragma unroll
      for (int n = 0; n < 4; ++n)
        acc[m][n] = mfma16(av[m], bv[n], acc[m][n]);
    __syncthreads();
  }

#pragma unroll
  for (int m = 0; m < 4; ++m) {
#pragma unroll
    for (int n = 0; n < 4; ++n) {
      const int gcol = tileN + wc + n * 16 + fr;
      const int growb = tileM + wr + m * 16 + fg * 4;
#pragma unroll
      for (int r = 0; r < 4; ++r) {
        const int grow = growb + r;
        float v = acc[m][n][r];
        if constexpr (EPI == EPI_GATES) {
          v += bias[gcol];   // b_ih + b_hh folded here
          ((u16*)Cp)[(size_t)grow * ldc + gcol] = f2b(v);
        } else if constexpr (EPI == EPI_H1) {
          v += bias[(grow >> 7) * 256 + gcol];
          v = fmaxf(v, 0.f);
          ((u16*)Cp)[(size_t)grow * ldc + gcol] = f2b(v);
        } else if constexpr (EPI == EPI_H2) {
          v += bias[gcol];
          v = fmaxf(v, 0.f);
          ((u16*)Cp)[(size_t)grow * ldc + gcol] = f2b(v);
        } else {
          v += bias[gcol];
          ((float*)Cp)[(size_t)grow * ldc + gcol] = sigf(v);
        }
      }
    }
  }
}

// ---------------- fused LSTM scan + encoder + VQ + p1 ----------------
// 448 threads (7 waves), one block per batch element. W_hh lives in LDS as i8
// (k 0..191, 153.6KB dynamic-shared) + 4 reg dwords/worker (k 192..199).
// Worker r<400 computes gate rows {r, r+400} via v_dot4_i32_i8 (4 MACs/instr,
// no decode tax, ~80 live VGPRs -> no allocator spill by construction).
// LDS-throughput-bound: ~24 lane-linear ds_read_b128 per worker per step.
__global__ __launch_bounds__(448) void lstm_enc(
    const u16* __restrict__ gates, const uint4* __restrict__ W4g,
    const uint4* __restrict__ Wregg,
    const float* __restrict__ Wenc, const float* __restrict__ b_enc,
    const float* __restrict__ emb, const float* __restrict__ W1,
    const float* __restrict__ b1, const float* __restrict__ noise,
    float* __restrict__ p1) {
  extern __shared__ __attribute__((aligned(16))) char dynsm[];
  uint4* W4 = (uint4*)dynsm;                       // [12*800] uint4
  __shared__ __attribute__((aligned(16))) unsigned sh_hq[56];  // h as i8, k 0..223 (pad 0)
  __shared__ __attribute__((aligned(16))) float sh_hf[HID];
  __shared__ float sh_g[G4H];
  __shared__ __attribute__((aligned(16))) float sh_ze[LATENT];
  __shared__ float sh_zq[LATENT];
  __shared__ float sh_rd[448];
  __shared__ int sh_ri[448];
  const int r = threadIdx.x;
  const int b = blockIdx.x;
  const bool active = (r < 400);

  // stage W4 into LDS (9600 uint4, coalesced; L2-resident source)
  for (int i = r; i < 12 * 800; i += 448) W4[i] = W4g[i];
  uint4 wreg = active ? Wregg[r] : (uint4){0, 0, 0, 0};
  if (r < 56) sh_hq[r] = 0;
  if (r < HID) sh_hf[r] = 0.f;
  float c = 0.f;
  const u16* gp = gates + (size_t)b * TLEN * LDG + r;
  float gvA = 0.f, gvB = 0.f;
  if (active) { gvA = b2f(gp[0]); gvB = b2f(gp[400]); }
  __syncthreads();

  for (int t = 0; t < TLEN; ++t) {
    gp += LDG;
    float gvA_n = 0.f, gvB_n = 0.f;
    if (active && t + 1 < TLEN) { gvA_n = b2f(gp[0]); gvB_n = b2f(gp[400]); }

    if (active) {
      // h dwords 0..51 (uniform-address broadcast reads)
      unsigned hd[52];
#pragma unroll
      for (int j = 0; j < 13; ++j) {
        uint4 v = ((const uint4*)sh_hq)[j];
        hd[4 * j + 0] = v.x; hd[4 * j + 1] = v.y;
        hd[4 * j + 2] = v.z; hd[4 * j + 3] = v.w;
      }
      int accA = 0, accB = 0;
#pragma unroll
      for (int jb = 0; jb < 12; ++jb) {
        uint4 wA = W4[jb * 800 + r];
        uint4 wB = W4[jb * 800 + 400 + r];
        accA = dot4(wA.x, hd[4 * jb + 0], accA);
        accA = dot4(wA.y, hd[4 * jb + 1], accA);
        accA = dot4(wA.z, hd[4 * jb + 2], accA);
        accA = dot4(wA.w, hd[4 * jb + 3], accA);
        accB = dot4(wB.x, hd[4 * jb + 0], accB);
        accB = dot4(wB.y, hd[4 * jb + 1], accB);
        accB = dot4(wB.z, hd[4 * jb + 2], accB);
        accB = dot4(wB.w, hd[4 * jb + 3], accB);
      }
      // tail k 192..199 from registers
      accA = dot4(wreg.x, hd[48], accA);
      accA = dot4(wreg.y, hd[49], accA);
      accB = dot4(wreg.z, hd[48], accB);
      accB = dot4(wreg.w, hd[49], accB);
      sh_g[r] = gvA + (float)accA * ISCL;
      sh_g[r + 400] = gvB + (float)accB * ISCL;
    }
    __syncthreads();  // gates visible; all sh_hq reads complete
    if (r < HID) {
      float gi = sh_g[r], gf = sh_g[HID + r], gg = sh_g[2 * HID + r], go = sh_g[3 * HID + r];
      c = sigf(gf) * c + sigf(gi) * tanh_fast(gg);
      float h = sigf(go) * tanh_fast(c);
      sh_hf[r] = h;
      int q = __float2int_rn(h * HSCL);
      ((char*)sh_hq)[r] = (char)q;
    }
    __syncthreads();  // new h visible
    gvA = gvA_n; gvB = gvB_n;
  }

  // encoder: z_e = h @ Wenc^T + b_enc
  if (r < LATENT) {
    float z = b_enc[r];
#pragma unroll 4
    for (int k = 0; k < HID; ++k) z = fmaf(Wenc[(size_t)r * HID + k], sh_hf[k], z);
    sh_ze[r] = z;
  }
  __syncthreads();

  // VQ: argmin_k ||e_k||^2 - 2 z_e . e_k
  float best = INFINITY; int bi = 0;
  for (int k = r; k < NCODES; k += 448) {
    float d = 0.f;
#pragma unroll
    for (int q = 0; q < LATENT / 4; ++q) {
      float4 e = *(const float4*)&emb[(size_t)k * LATENT + q * 4];
      float4 z = *(const float4*)&sh_ze[q * 4];
      d += e.x * (e.x - 2.f * z.x) + e.y * (e.y - 2.f * z.y)
         + e.z * (e.z - 2.f * z.z) + e.w * (e.w - 2.f * z.w);
    }
    if (d < best) { best = d; bi = k; }
  }
  sh_rd[r] = best; sh_ri[r] = bi;
  __syncthreads();
  for (int s = 256; s > 0; s >>= 1) {
    if (r < s && r + s < 448) {
      float od = sh_rd[r + s]; int oi = sh_ri[r + s];
      if (od < sh_rd[r] || (od == sh_rd[r] && oi < sh_ri[r])) { sh_rd[r] = od; sh_ri[r] = oi; }
    }
    __syncthreads();
  }
  const int kmin = sh_ri[0];
  if (r < LATENT) sh_zq[r] = emb[(size_t)kmin * LATENT + r];
  __syncthreads();

  // p1[b][j] = b1 + W1[:,0:128].zq + W1[:,1664:2432].noise  (pad cols 200..255 = 0)
  if (r < 256) {
    float v = 0.f;
    if (r < HID) {
      v = b1[r];
      const float* wrow = W1 + (size_t)r * 2432;
#pragma unroll 4
      for (int d = 0; d < LATENT; ++d) v = fmaf(wrow[d], sh_zq[d], v);
      const float* nz = noise + (size_t)b * DIN;
#pragma unroll 4
      for (int d = 0; d < DIN; ++d) v = fmaf(wrow[1664 + d], nz[d], v);
    }
    p1[b * 256 + r] = v;
  }
}

// ---------------- host ----------------
extern "C" void kernel_launch(void* const* d_in, const int* in_sizes, int n_in,
                              void* d_out, int out_size, void* d_ws, size_t ws_size,
                              hipStream_t stream) {
  const float* x     = (const float*)d_in[0];
  const float* cond  = (const float*)d_in[1];
  const float* noise = (const float*)d_in[2];
  const float* W_ih  = (const float*)d_in[3];
  const float* W_hh  = (const float*)d_in[4];
  const float* b_ih  = (const float*)d_in[5];
  const float* b_hh  = (const float*)d_in[6];
  const float* W_enc = (const float*)d_in[7];
  const float* b_enc = (const float*)d_in[8];
  const float* emb   = (const float*)d_in[9];
  const float* W1    = (const float*)d_in[10];
  const float* b1    = (const float*)d_in[11];
  const float* W2    = (const float*)d_in[12];
  const float* b2    = (const float*)d_in[13];
  const float* W3    = (const float*)d_in[14];
  const float* b3    = (const float*)d_in[15];

  char* ws = (char*)d_ws;
  size_t off = 0;
  auto alloc = [&](size_t bytes) -> void* {
    void* p = ws + off; off += (bytes + 255) & ~(size_t)255; return p;
  };
  u16*      W_ihb = (u16*)alloc((size_t)896 * 768 * 2);
  u16*      W1cb  = (u16*)alloc((size_t)256 * 1536 * 2);
  u16*      W2b   = (u16*)alloc((size_t)512 * 256 * 2);
  u16*      W3b   = (u16*)alloc((size_t)768 * 512 * 2);
  float*    b2p   = (float*)alloc(512 * 4);
  unsigned* W4    = (unsigned*)alloc((size_t)W4_BYTES);
  unsigned* Wreg  = (unsigned*)alloc((size_t)400 * 4 * 4);
  float*    biasc = (float*)alloc(LDG * 4);
  u16*      gates = (u16*)alloc((size_t)MROWS * LDG * 2);
  float*    p1    = (float*)alloc(256 * 256 * 4);
  u16*      h1    = (u16*)alloc((size_t)MROWS * LDH1 * 2);
  u16*      h2    = (u16*)alloc((size_t)MROWS * LDH2 * 2);

  cvt_pad<<<dim3((896 * 768 + 255) / 256), 256, 0, stream>>>(W_ih, W_ihb, 800, 768, 768, 0, 896, 768);
  cvt_pad<<<dim3((256 * 1536 + 255) / 256), 256, 0, stream>>>(W1, W1cb, 200, 1536, 2432, 128, 256, 1536);
  cvt_pad<<<dim3((512 * 256 + 255) / 256), 256, 0, stream>>>(W2, W2b, 400, 200, 200, 0, 512, 256);
  cvt_pad<<<dim3((768 * 512 + 255) / 256), 256, 0, stream>>>(W3, W3b, 768, 400, 400, 0, 768, 512);
  pad_f32<<<dim3(2), 256, 0, stream>>>(b2, b2p, 400, 512);
  pack_whh_i8<<<dim3((800 * 50 + 255) / 256), 256, 0, stream>>>(W_hh, W4, Wreg, b_ih, b_hh, biasc);

  // gates = x @ W_ih^T + (b_ih + b_hh), bf16 out, ld 896
  gemm_bf16<true, EPI_GATES><<<dim3(LDG / 128, MROWS / 128), 256, 0, stream>>>(
      x, W_ihb, gates, 768, LDG, biasc);

  // LSTM scan + encoder + VQ + p1 (W_hh in dynamic LDS, i8)
  static bool attr_set = false;
  if (!attr_set) {
    (void)hipFuncSetAttribute((const void*)lstm_enc,
                              hipFuncAttributeMaxDynamicSharedMemorySize, W4_BYTES);
    attr_set = true;
  }
  lstm_enc<<<dim3(NB), 448, W4_BYTES, stream>>>(gates, (const uint4*)W4, (const uint4*)Wreg,
                                                W_enc, b_enc, emb, W1, b1, noise, p1);

  // h1 = relu(cond @ W1c^T + p1[b])
  gemm_bf16<true, EPI_H1><<<dim3(LDH1 / 128, MROWS / 128), 256, 0, stream>>>(
      cond, W1cb, h1, DCOND, LDH1, p1);
  // h2 = relu(h1 @ W2^T + b2)
  gemm_bf16<false, EPI_H2><<<dim3(LDH2 / 128, MROWS / 128), 256, 0, stream>>>(
      h1, W2b, h2, LDH1, LDH2, b2p);
  // out = sigmoid(h2 @ W3^T + b3)
  gemm_bf16<false, EPI_OUT><<<dim3(NOUT / 128, MROWS / 128), 256, 0, stream>>>(
      h2, W3b, (float*)d_out, LDH2, NOUT, b3);
}